// Round 2
// baseline (2240.151 us; speedup 1.0000x reference)
//
#include <hip/hip_runtime.h>
#include <hip/hip_bf16.h>

// GNN: node_proj + edge scatter_mean/proj -> concat -> GAT(512->4x64) -> ELU
//      -> GAT(256->4x64) -> ELU -> out_proj. ALL tensors float32 (per ref).
// R1: fix dtypes (f32 everywhere, int32 edge_index). VALU GEMM + atomic scatter.

#define HID 256
#define HEADS 4
#define CH 64

// ---------------- edge_attr scatter-mean ----------------
__global__ __launch_bounds__(256) void edge_sum_kernel(
    const float* __restrict__ ea, const int* __restrict__ dst,
    float* __restrict__ nef, float* __restrict__ cnt, int E)
{
    int idx = blockIdx.x * 256 + threadIdx.x;
    if (idx >= E * 16) return;
    int e = idx >> 4, f = idx & 15;
    int d = dst[e];
    atomicAdd(&nef[d * 16 + f], ea[idx]);
    if (f == 0) atomicAdd(&cnt[d], 1.0f);
}

__global__ __launch_bounds__(256) void nef_div_kernel(
    float* __restrict__ nef, const float* __restrict__ cnt, int N)
{
    int idx = blockIdx.x * 256 + threadIdx.x;
    if (idx >= N * 16) return;
    nef[idx] = nef[idx] / fmaxf(cnt[idx >> 4], 1.0f);
}

// ---------------- tiled f32 GEMM: C = A @ W (+bias) ----------------
// A: [N x K] f32, W: [K x M] f32 row-major, M multiple of 64.
#define BM 64
#define BN 64
#define BK 16

__global__ __launch_bounds__(256) void gemm_kernel(
    const float* __restrict__ A, int lda,
    const float* __restrict__ W,
    const float* __restrict__ bias,
    float* __restrict__ C, int ldc,
    int Nrows, int K, int M)
{
    __shared__ float As[BK][BM];
    __shared__ float Bs[BK][BN];
    int block_row = blockIdx.y * BM;
    int block_col = blockIdx.x * BN;
    int tid = threadIdx.x;
    int tx = tid & 15;      // col group
    int ty = tid >> 4;      // row group
    float acc[4][4] = {};

    for (int k0 = 0; k0 < K; k0 += BK) {
        // A tile: 64 rows x 16 k. thread: row tid>>2, 4 consecutive k's.
        int r = tid >> 2;
        int kk = (tid & 3) * 4;
        int gr = block_row + r;
        #pragma unroll
        for (int i = 0; i < 4; i++) {
            float v = 0.0f;
            if (gr < Nrows) v = A[(size_t)gr * lda + k0 + kk + i];
            As[kk + i][r] = v;
        }
        // W tile: 16 k x 64 cols. thread: k row tid>>4, 4 consecutive cols.
        int wr = tid >> 4;
        int wc = (tid & 15) * 4;
        #pragma unroll
        for (int i = 0; i < 4; i++) {
            Bs[wr][wc + i] = W[(size_t)(k0 + wr) * M + block_col + wc + i];
        }
        __syncthreads();
        #pragma unroll
        for (int kk2 = 0; kk2 < BK; kk2++) {
            float a[4], b[4];
            #pragma unroll
            for (int i = 0; i < 4; i++) a[i] = As[kk2][ty * 4 + i];
            #pragma unroll
            for (int j = 0; j < 4; j++) b[j] = Bs[kk2][tx * 4 + j];
            #pragma unroll
            for (int i = 0; i < 4; i++)
                #pragma unroll
                for (int j = 0; j < 4; j++)
                    acc[i][j] += a[i] * b[j];
        }
        __syncthreads();
    }

    #pragma unroll
    for (int i = 0; i < 4; i++) {
        int gr = block_row + ty * 4 + i;
        if (gr >= Nrows) continue;
        #pragma unroll
        for (int j = 0; j < 4; j++) {
            int gc = block_col + tx * 4 + j;
            float v = acc[i][j];
            if (bias) v += bias[gc];
            C[(size_t)gr * ldc + gc] = v;
        }
    }
}

// ---------------- GAT per-node prep: attention dots + zero accum/denom ------
__global__ __launch_bounds__(256) void gat_prep_kernel(
    const float* __restrict__ xh,
    const float* __restrict__ att_src, const float* __restrict__ att_dst,
    float* __restrict__ a_src, float* __restrict__ a_dst,
    float* __restrict__ denom, float* __restrict__ accum, int N)
{
    int n = blockIdx.x;
    int t = threadIdx.x;
    int h = t >> 6, c = t & 63;
    float v = xh[(size_t)n * 256 + t];
    float s = v * att_src[t];
    float d = v * att_dst[t];
    #pragma unroll
    for (int o = 32; o > 0; o >>= 1) {
        s += __shfl_down(s, o, 64);
        d += __shfl_down(d, o, 64);
    }
    if (c == 0) {
        a_src[n * 4 + h] = s;
        a_dst[n * 4 + h] = d;
        denom[n * 4 + h] = 0.0f;
    }
    accum[(size_t)n * 256 + t] = 0.0f;
}

// ---------------- softmax denominator over edges (incl. self loops) --------
__global__ __launch_bounds__(256) void gat_denom_kernel(
    const int* __restrict__ src, const int* __restrict__ dst,
    const float* __restrict__ a_src, const float* __restrict__ a_dst,
    float* __restrict__ denom, int E, int N)
{
    int idx = blockIdx.x * 256 + threadIdx.x;
    int tot = (E + N) * 4;
    if (idx >= tot) return;
    int e = idx >> 2, h = idx & 3;
    int s, d;
    if (e < E) { s = src[e]; d = dst[e]; } else { s = e - E; d = s; }
    float l = a_src[s * 4 + h] + a_dst[d * 4 + h];
    l = (l > 0.0f) ? l : 0.2f * l;
    atomicAdd(&denom[d * 4 + h], __expf(l));
}

// ---------------- weighted scatter-add of messages -------------------------
__global__ __launch_bounds__(256) void gat_agg_kernel(
    const float* __restrict__ xh,
    const int* __restrict__ src, const int* __restrict__ dst,
    const float* __restrict__ a_src, const float* __restrict__ a_dst,
    const float* __restrict__ denom,
    float* __restrict__ accum, int E, int N)
{
    int e = blockIdx.x;
    int t = threadIdx.x;
    int h = t >> 6;
    int s, d;
    if (e < E) { s = src[e]; d = dst[e]; } else { s = e - E; d = s; }
    float l = a_src[s * 4 + h] + a_dst[d * 4 + h];
    l = (l > 0.0f) ? l : 0.2f * l;
    float alpha = __expf(l) / denom[d * 4 + h];
    float v = xh[(size_t)s * 256 + t] * alpha;
    atomicAdd(&accum[(size_t)d * 256 + t], v);
}

// ---------------- bias + ELU (in place) ------------------------------------
__global__ __launch_bounds__(256) void elu_bias_kernel(
    float* __restrict__ x, const float* __restrict__ bias, int total)
{
    int i = blockIdx.x * 256 + threadIdx.x;
    if (i >= total) return;
    float v = x[i] + bias[i & 255];
    x[i] = (v > 0.0f) ? v : (__expf(v) - 1.0f);
}

extern "C" void kernel_launch(void* const* d_in, const int* in_sizes, int n_in,
                              void* d_out, int out_size, void* d_ws, size_t ws_size,
                              hipStream_t stream)
{
    const float* node_feats = (const float*)d_in[0];
    const float* edge_attr  = (const float*)d_in[1];
    const float* Wnp = (const float*)d_in[2];
    const float* bnp = (const float*)d_in[3];
    const float* Wep = (const float*)d_in[4];
    const float* bep = (const float*)d_in[5];
    const float* Wg1 = (const float*)d_in[6];
    const float* as1 = (const float*)d_in[7];
    const float* ad1 = (const float*)d_in[8];
    const float* bg1 = (const float*)d_in[9];
    const float* Wg2 = (const float*)d_in[10];
    const float* as2 = (const float*)d_in[11];
    const float* ad2 = (const float*)d_in[12];
    const float* bg2 = (const float*)d_in[13];
    const float* Wo  = (const float*)d_in[14];
    const float* bo  = (const float*)d_in[15];
    const int*   ei  = (const int*)d_in[16];

    const int N = in_sizes[0] / 128;   // 50000
    const int E = in_sizes[16] / 2;    // 800000
    const int* src = ei;
    const int* dst = ei + E;

    // workspace layout (f32)
    float* ws = (float*)d_ws;
    size_t off = 0;
    float* bufA  = ws + off; off += (size_t)N * 512;  // x2; later accum1/x3 (lo), accum2/x4 (hi)
    float* bufB  = ws + off; off += (size_t)N * 256;  // xh
    float* nef   = ws + off; off += (size_t)N * 16;
    float* cnt   = ws + off; off += (size_t)N;
    float* a_src = ws + off; off += (size_t)N * 4;
    float* a_dst = ws + off; off += (size_t)N * 4;
    float* denom = ws + off; off += (size_t)N * 4;

    float* A_lo = bufA;                       // [N,256] accum1 / x3
    float* A_hi = bufA + (size_t)N * 256;     // [N,256] accum2 / x4

    float* out = (float*)d_out;

    dim3 gemm_grid(256 / BN, (N + BM - 1) / BM);

    // 1) edge scatter-mean -> nef [N,16]
    hipMemsetAsync(nef, 0, ((size_t)N * 16 + N) * sizeof(float), stream);
    edge_sum_kernel<<<(E * 16 + 255) / 256, 256, 0, stream>>>(edge_attr, dst, nef, cnt, E);
    nef_div_kernel<<<(N * 16 + 255) / 256, 256, 0, stream>>>(nef, cnt, N);

    // 2) x2 = [ node_feats@Wnp + bnp | nef@Wep + bep ]  -> bufA [N,512]
    gemm_kernel<<<gemm_grid, 256, 0, stream>>>(
        node_feats, 128, Wnp, bnp, bufA, 512, N, 128, 256);
    gemm_kernel<<<gemm_grid, 256, 0, stream>>>(
        nef, 16, Wep, bep, bufA + 256, 512, N, 16, 256);

    // 3) GAT layer 1
    gemm_kernel<<<gemm_grid, 256, 0, stream>>>(
        bufA, 512, Wg1, nullptr, bufB, 256, N, 512, 256);
    gat_prep_kernel<<<N, 256, 0, stream>>>(bufB, as1, ad1, a_src, a_dst, denom, A_lo, N);
    gat_denom_kernel<<<(((E + N) * 4) + 255) / 256, 256, 0, stream>>>(
        src, dst, a_src, a_dst, denom, E, N);
    gat_agg_kernel<<<E + N, 256, 0, stream>>>(
        bufB, src, dst, a_src, a_dst, denom, A_lo, E, N);
    elu_bias_kernel<<<((N * 256) + 255) / 256, 256, 0, stream>>>(A_lo, bg1, N * 256);

    // 4) GAT layer 2
    gemm_kernel<<<gemm_grid, 256, 0, stream>>>(
        A_lo, 256, Wg2, nullptr, bufB, 256, N, 256, 256);
    gat_prep_kernel<<<N, 256, 0, stream>>>(bufB, as2, ad2, a_src, a_dst, denom, A_hi, N);
    gat_denom_kernel<<<(((E + N) * 4) + 255) / 256, 256, 0, stream>>>(
        src, dst, a_src, a_dst, denom, E, N);
    gat_agg_kernel<<<E + N, 256, 0, stream>>>(
        bufB, src, dst, a_src, a_dst, denom, A_hi, E, N);
    elu_bias_kernel<<<((N * 256) + 255) / 256, 256, 0, stream>>>(A_hi, bg2, N * 256);

    // 5) out = x4 @ Wo + bo  -> d_out (f32)
    gemm_kernel<<<gemm_grid, 256, 0, stream>>>(
        A_hi, 256, Wo, bo, out, 256, N, 256, 256);
}

// Round 3
// 1214.507 us; speedup vs baseline: 1.8445x; 1.8445x over previous
//
#include <hip/hip_runtime.h>
#include <hip/hip_bf16.h>

// GNN: node_proj + edge scatter_mean/proj -> concat -> GAT(512->4x64) -> ELU
//      -> GAT(256->4x64) -> ELU -> out_proj. ALL tensors float32 (per ref).
// R2: CSR-by-dst aggregation (no f32 atomics on accum/denom); fused
//     bias+ELU into the aggregation epilogue. GEMMs still VALU f32.

#define HEADS 4

// ============================ CSR construction =============================

__global__ __launch_bounds__(256) void count_kernel(
    const int* __restrict__ dst, int* __restrict__ cnt, int E)
{
    int e = blockIdx.x * 256 + threadIdx.x;
    if (e < E) atomicAdd(&cnt[dst[e]], 1);
}

// chunk sums of (cnt[n]+1) over 256-node chunks
__global__ __launch_bounds__(256) void scan1_kernel(
    const int* __restrict__ cnt, int* __restrict__ chunk_sum, int N)
{
    __shared__ int sd[256];
    int t = threadIdx.x;
    int n = blockIdx.x * 256 + t;
    sd[t] = (n < N) ? (cnt[n] + 1) : 0;
    __syncthreads();
    for (int o = 128; o > 0; o >>= 1) {
        if (t < o) sd[t] += sd[t + o];
        __syncthreads();
    }
    if (t == 0) chunk_sum[blockIdx.x] = sd[0];
}

__global__ void scan2_kernel(const int* __restrict__ chunk_sum,
                             int* __restrict__ chunk_off, int nchunk)
{
    int acc = 0;
    for (int i = 0; i < nchunk; i++) {
        chunk_off[i] = acc;
        acc += chunk_sum[i];
    }
}

// per-node rowptr + self-loop slot + fill pointer init
__global__ __launch_bounds__(256) void scan3_kernel(
    const int* __restrict__ cnt, const int* __restrict__ chunk_off,
    int* __restrict__ rowptr, int* __restrict__ fillptr,
    int* __restrict__ col, int* __restrict__ eid, int N)
{
    __shared__ int sd[256];
    int t = threadIdx.x;
    int n = blockIdx.x * 256 + t;
    int v = (n < N) ? (cnt[n] + 1) : 0;
    sd[t] = v;
    __syncthreads();
    // Hillis-Steele inclusive scan
    for (int o = 1; o < 256; o <<= 1) {
        int x = (t >= o) ? sd[t - o] : 0;
        __syncthreads();
        sd[t] += x;
        __syncthreads();
    }
    if (n < N) {
        int incl = sd[t];
        int r = chunk_off[blockIdx.x] + incl - v;
        rowptr[n] = r;
        col[r] = n;        // self loop, first entry
        eid[r] = -1;
        fillptr[n] = r + 1;
        if (n == N - 1) rowptr[N] = chunk_off[blockIdx.x] + incl;
    }
}

__global__ __launch_bounds__(256) void fill_kernel(
    const int* __restrict__ src, const int* __restrict__ dst,
    int* __restrict__ fillptr, int* __restrict__ col, int* __restrict__ eid, int E)
{
    int e = blockIdx.x * 256 + threadIdx.x;
    if (e >= E) return;
    int d = dst[e];
    int p = atomicAdd(&fillptr[d], 1);
    col[p] = src[e];
    eid[p] = e;
}

// ================= edge_attr scatter-mean via CSR (one wave/node) ==========
__global__ __launch_bounds__(64) void nef_csr_kernel(
    const float* __restrict__ ea, const int* __restrict__ rowptr,
    const int* __restrict__ eid, float* __restrict__ nef, int N)
{
    int n = blockIdx.x;
    int t = threadIdx.x;
    int f = t & 15, g = t >> 4;          // 4 groups of 16 features
    int base = rowptr[n], end = rowptr[n + 1];
    int deg = end - base - 1;            // real in-degree (excl self loop)
    float acc = 0.0f;
    for (int j = base + 1 + g; j < end; j += 4) {
        int e = eid[j];
        acc += ea[(size_t)e * 16 + f];
    }
    acc += __shfl_down(acc, 32, 64);
    acc += __shfl_down(acc, 16, 64);
    if (t < 16) nef[n * 16 + f] = acc / fmaxf((float)deg, 1.0f);
}

// ---------------- tiled f32 GEMM: C = A @ W (+bias) ----------------
#define BM 64
#define BN 64
#define BK 16

__global__ __launch_bounds__(256) void gemm_kernel(
    const float* __restrict__ A, int lda,
    const float* __restrict__ W,
    const float* __restrict__ bias,
    float* __restrict__ C, int ldc,
    int Nrows, int K, int M)
{
    __shared__ float As[BK][BM];
    __shared__ float Bs[BK][BN];
    int block_row = blockIdx.y * BM;
    int block_col = blockIdx.x * BN;
    int tid = threadIdx.x;
    int tx = tid & 15;
    int ty = tid >> 4;
    float acc[4][4] = {};

    for (int k0 = 0; k0 < K; k0 += BK) {
        int r = tid >> 2;
        int kk = (tid & 3) * 4;
        int gr = block_row + r;
        #pragma unroll
        for (int i = 0; i < 4; i++) {
            float v = 0.0f;
            if (gr < Nrows) v = A[(size_t)gr * lda + k0 + kk + i];
            As[kk + i][r] = v;
        }
        int wr = tid >> 4;
        int wc = (tid & 15) * 4;
        #pragma unroll
        for (int i = 0; i < 4; i++) {
            Bs[wr][wc + i] = W[(size_t)(k0 + wr) * M + block_col + wc + i];
        }
        __syncthreads();
        #pragma unroll
        for (int kk2 = 0; kk2 < BK; kk2++) {
            float a[4], b[4];
            #pragma unroll
            for (int i = 0; i < 4; i++) a[i] = As[kk2][ty * 4 + i];
            #pragma unroll
            for (int j = 0; j < 4; j++) b[j] = Bs[kk2][tx * 4 + j];
            #pragma unroll
            for (int i = 0; i < 4; i++)
                #pragma unroll
                for (int j = 0; j < 4; j++)
                    acc[i][j] += a[i] * b[j];
        }
        __syncthreads();
    }

    #pragma unroll
    for (int i = 0; i < 4; i++) {
        int gr = block_row + ty * 4 + i;
        if (gr >= Nrows) continue;
        #pragma unroll
        for (int j = 0; j < 4; j++) {
            int gc = block_col + tx * 4 + j;
            float v = acc[i][j];
            if (bias) v += bias[gc];
            C[(size_t)gr * ldc + gc] = v;
        }
    }
}

// ---------------- GAT per-node attention dots ------------------------------
__global__ __launch_bounds__(256) void gat_prep_kernel(
    const float* __restrict__ xh,
    const float* __restrict__ att_src, const float* __restrict__ att_dst,
    float* __restrict__ a_src, float* __restrict__ a_dst, int N)
{
    int n = blockIdx.x;
    int t = threadIdx.x;
    int h = t >> 6, c = t & 63;
    float v = xh[(size_t)n * 256 + t];
    float s = v * att_src[t];
    float d = v * att_dst[t];
    #pragma unroll
    for (int o = 32; o > 0; o >>= 1) {
        s += __shfl_down(s, o, 64);
        d += __shfl_down(d, o, 64);
    }
    if (c == 0) {
        a_src[n * 4 + h] = s;
        a_dst[n * 4 + h] = d;
    }
}

// ============ CSR aggregation: softmax + weighted sum + bias + ELU =========
// one block (256 thr = 4 waves = 4 heads) per destination node
__global__ __launch_bounds__(256) void gat_agg_csr_kernel(
    const float* __restrict__ xh,
    const int* __restrict__ rowptr, const int* __restrict__ col,
    const float* __restrict__ a_src, const float* __restrict__ a_dst,
    const float* __restrict__ bias,
    float* __restrict__ outbuf, int N)
{
    __shared__ float denom_sh[HEADS];
    int n = blockIdx.x;
    int t = threadIdx.x;
    int h = t >> 6, c = t & 63;
    int base = rowptr[n], end = rowptr[n + 1];
    float adst = a_dst[n * 4 + h];

    // pass 1: denominator per head (wave h handles head h, lanes stride edges)
    float part = 0.0f;
    for (int j = base + c; j < end; j += 64) {
        float l = a_src[col[j] * 4 + h] + adst;
        l = (l > 0.0f) ? l : 0.2f * l;
        part += __expf(l);
    }
    #pragma unroll
    for (int o = 32; o > 0; o >>= 1) part += __shfl_down(part, o, 64);
    if (c == 0) denom_sh[h] = part;
    __syncthreads();
    float inv = 1.0f / denom_sh[h];

    // pass 2: sequential weighted accumulation over in-edges
    float acc = 0.0f;
    for (int j = base; j < end; j++) {
        int s = col[j];
        float l = a_src[s * 4 + h] + adst;
        l = (l > 0.0f) ? l : 0.2f * l;
        float w = __expf(l) * inv;
        acc += w * xh[(size_t)s * 256 + t];
    }
    float v = acc + bias[t];
    outbuf[(size_t)n * 256 + t] = (v > 0.0f) ? v : (__expf(v) - 1.0f);
}

// ===========================================================================

extern "C" void kernel_launch(void* const* d_in, const int* in_sizes, int n_in,
                              void* d_out, int out_size, void* d_ws, size_t ws_size,
                              hipStream_t stream)
{
    const float* node_feats = (const float*)d_in[0];
    const float* edge_attr  = (const float*)d_in[1];
    const float* Wnp = (const float*)d_in[2];
    const float* bnp = (const float*)d_in[3];
    const float* Wep = (const float*)d_in[4];
    const float* bep = (const float*)d_in[5];
    const float* Wg1 = (const float*)d_in[6];
    const float* as1 = (const float*)d_in[7];
    const float* ad1 = (const float*)d_in[8];
    const float* bg1 = (const float*)d_in[9];
    const float* Wg2 = (const float*)d_in[10];
    const float* as2 = (const float*)d_in[11];
    const float* ad2 = (const float*)d_in[12];
    const float* bg2 = (const float*)d_in[13];
    const float* Wo  = (const float*)d_in[14];
    const float* bo  = (const float*)d_in[15];
    const int*   ei  = (const int*)d_in[16];

    const int N = in_sizes[0] / 128;   // 50000
    const int E = in_sizes[16] / 2;    // 800000
    const int* src = ei;
    const int* dst = ei + E;
    const int nchunk = (N + 255) / 256;
    const int EN = E + N;              // CSR entries incl self loops

    // ---- workspace layout ----
    float* ws = (float*)d_ws;
    size_t off = 0;
    float* bufA  = ws + off; off += (size_t)N * 512;  // x2; halves reused as x3/x4
    float* bufB  = ws + off; off += (size_t)N * 256;  // xh
    float* nef   = ws + off; off += (size_t)N * 16;
    float* a_src = ws + off; off += (size_t)N * 4;
    float* a_dst = ws + off; off += (size_t)N * 4;
    int* iws = (int*)(ws + off);
    size_t ioff = 0;
    int* cnt       = iws + ioff; ioff += N;
    int* rowptr    = iws + ioff; ioff += N + 1;
    int* fillptr   = iws + ioff; ioff += N;
    int* chunk_sum = iws + ioff; ioff += nchunk;
    int* chunk_off = iws + ioff; ioff += nchunk;
    int* col       = iws + ioff; ioff += EN;
    int* eid       = iws + ioff; ioff += EN;

    float* A_lo = bufA;                       // [N,256] x3
    float* A_hi = bufA + (size_t)N * 256;     // [N,256] x4
    float* out = (float*)d_out;

    dim3 gemm_grid(256 / BN, (N + BM - 1) / BM);

    // ---- CSR build ----
    hipMemsetAsync(cnt, 0, (size_t)N * sizeof(int), stream);
    count_kernel<<<(E + 255) / 256, 256, 0, stream>>>(dst, cnt, E);
    scan1_kernel<<<nchunk, 256, 0, stream>>>(cnt, chunk_sum, N);
    scan2_kernel<<<1, 1, 0, stream>>>(chunk_sum, chunk_off, nchunk);
    scan3_kernel<<<nchunk, 256, 0, stream>>>(cnt, chunk_off, rowptr, fillptr, col, eid, N);
    fill_kernel<<<(E + 255) / 256, 256, 0, stream>>>(src, dst, fillptr, col, eid, E);

    // ---- edge scatter-mean -> nef [N,16] ----
    nef_csr_kernel<<<N, 64, 0, stream>>>(edge_attr, rowptr, eid, nef, N);

    // ---- x2 = [ node_feats@Wnp + bnp | nef@Wep + bep ] -> bufA [N,512] ----
    gemm_kernel<<<gemm_grid, 256, 0, stream>>>(
        node_feats, 128, Wnp, bnp, bufA, 512, N, 128, 256);
    gemm_kernel<<<gemm_grid, 256, 0, stream>>>(
        nef, 16, Wep, bep, bufA + 256, 512, N, 16, 256);

    // ---- GAT layer 1 ----
    gemm_kernel<<<gemm_grid, 256, 0, stream>>>(
        bufA, 512, Wg1, nullptr, bufB, 256, N, 512, 256);
    gat_prep_kernel<<<N, 256, 0, stream>>>(bufB, as1, ad1, a_src, a_dst, N);
    gat_agg_csr_kernel<<<N, 256, 0, stream>>>(
        bufB, rowptr, col, a_src, a_dst, bg1, A_lo, N);

    // ---- GAT layer 2 ----
    gemm_kernel<<<gemm_grid, 256, 0, stream>>>(
        A_lo, 256, Wg2, nullptr, bufB, 256, N, 256, 256);
    gat_prep_kernel<<<N, 256, 0, stream>>>(bufB, as2, ad2, a_src, a_dst, N);
    gat_agg_csr_kernel<<<N, 256, 0, stream>>>(
        bufB, rowptr, col, a_src, a_dst, bg2, A_hi, N);

    // ---- out = x4 @ Wo + bo -> d_out ----
    gemm_kernel<<<gemm_grid, 256, 0, stream>>>(
        A_hi, 256, Wo, bo, out, 256, N, 256, 256);
}

// Round 4
// 1035.264 us; speedup vs baseline: 2.1638x; 1.1731x over previous
//
#include <hip/hip_runtime.h>
#include <hip/hip_bf16.h>

// GNN: node_proj + edge scatter_mean/proj -> concat -> GAT(512->4x64) -> ELU
//      -> GAT(256->4x64) -> ELU -> out_proj. ALL tensors float32 (per ref).
// R3: all GEMMs via MFMA bf16x3 (hi/lo split, 3 MFMA per tile). Weights
//     packed to B-fragment order once; activations produced as hi/lo bf16
//     by producer epilogues. Aggregation stays f32 CSR (R2 structure).

#define HEADS 4

typedef __attribute__((ext_vector_type(8))) short bf16x8;
typedef __attribute__((ext_vector_type(4))) float f32x4;

__device__ __forceinline__ unsigned short f2b(float v) {
    __hip_bfloat16 b = __float2bfloat16(v);
    return __builtin_bit_cast(unsigned short, b);
}
__device__ __forceinline__ float b2f(unsigned short u) {
    __hip_bfloat16 b = __builtin_bit_cast(__hip_bfloat16, u);
    return __bfloat162float(b);
}
__device__ __forceinline__ void split_hilo(float v, unsigned short& h, unsigned short& l) {
    h = f2b(v);
    l = f2b(v - b2f(h));
}

// ============================ CSR construction =============================

__global__ __launch_bounds__(256) void count_kernel(
    const int* __restrict__ dst, int* __restrict__ cnt, int E)
{
    int e = blockIdx.x * 256 + threadIdx.x;
    if (e < E) atomicAdd(&cnt[dst[e]], 1);
}

__global__ __launch_bounds__(256) void scan1_kernel(
    const int* __restrict__ cnt, int* __restrict__ chunk_sum, int N)
{
    __shared__ int sd[256];
    int t = threadIdx.x;
    int n = blockIdx.x * 256 + t;
    sd[t] = (n < N) ? (cnt[n] + 1) : 0;
    __syncthreads();
    for (int o = 128; o > 0; o >>= 1) {
        if (t < o) sd[t] += sd[t + o];
        __syncthreads();
    }
    if (t == 0) chunk_sum[blockIdx.x] = sd[0];
}

__global__ void scan2_kernel(const int* __restrict__ chunk_sum,
                             int* __restrict__ chunk_off, int nchunk)
{
    int acc = 0;
    for (int i = 0; i < nchunk; i++) {
        chunk_off[i] = acc;
        acc += chunk_sum[i];
    }
}

__global__ __launch_bounds__(256) void scan3_kernel(
    const int* __restrict__ cnt, const int* __restrict__ chunk_off,
    int* __restrict__ rowptr, int* __restrict__ fillptr,
    int* __restrict__ col, int* __restrict__ eid, int N)
{
    __shared__ int sd[256];
    int t = threadIdx.x;
    int n = blockIdx.x * 256 + t;
    int v = (n < N) ? (cnt[n] + 1) : 0;
    sd[t] = v;
    __syncthreads();
    for (int o = 1; o < 256; o <<= 1) {
        int x = (t >= o) ? sd[t - o] : 0;
        __syncthreads();
        sd[t] += x;
        __syncthreads();
    }
    if (n < N) {
        int incl = sd[t];
        int r = chunk_off[blockIdx.x] + incl - v;
        rowptr[n] = r;
        col[r] = n;        // self loop, first entry
        eid[r] = -1;
        fillptr[n] = r + 1;
        if (n == N - 1) rowptr[N] = chunk_off[blockIdx.x] + incl;
    }
}

__global__ __launch_bounds__(256) void fill_kernel(
    const int* __restrict__ src, const int* __restrict__ dst,
    int* __restrict__ fillptr, int* __restrict__ col, int* __restrict__ eid, int E)
{
    int e = blockIdx.x * 256 + threadIdx.x;
    if (e >= E) return;
    int d = dst[e];
    int p = atomicAdd(&fillptr[d], 1);
    col[p] = src[e];
    eid[p] = e;
}

// ====== edge_attr scatter-mean via CSR -> hi/lo bf16 [N x 32] (K-padded) ===
__global__ __launch_bounds__(64) void nef_csr_kernel(
    const float* __restrict__ ea, const int* __restrict__ rowptr,
    const int* __restrict__ eid,
    unsigned short* __restrict__ nefH, unsigned short* __restrict__ nefL, int N)
{
    int n = blockIdx.x;
    int t = threadIdx.x;
    int f = t & 15, g = t >> 4;
    int base = rowptr[n], end = rowptr[n + 1];
    int deg = end - base - 1;
    float acc = 0.0f;
    for (int j = base + 1 + g; j < end; j += 4) {
        int e = eid[j];
        acc += ea[(size_t)e * 16 + f];
    }
    acc += __shfl_down(acc, 32, 64);
    acc += __shfl_down(acc, 16, 64);
    if (t < 16) {
        float v = acc / fmaxf((float)deg, 1.0f);
        unsigned short h, l;
        split_hilo(v, h, l);
        nefH[(size_t)n * 32 + t] = h;
        nefL[(size_t)n * 32 + t] = l;
    } else if (t < 32) {
        nefH[(size_t)n * 32 + t] = 0;
        nefL[(size_t)n * 32 + t] = 0;
    }
}

// ============ convert f32 -> hi/lo bf16 (2 elems per thread) ===============
__global__ __launch_bounds__(256) void conv_hilo_kernel(
    const float* __restrict__ X,
    unsigned short* __restrict__ H, unsigned short* __restrict__ L, int total)
{
    int base = (blockIdx.x * 256 + threadIdx.x) * 2;
    if (base >= total) return;
    #pragma unroll
    for (int i = 0; i < 2; i++) {
        unsigned short h, l;
        split_hilo(X[base + i], h, l);
        H[base + i] = h;
        L[base + i] = l;
    }
}

// ============ pack weights [K x 256] -> B-fragment order, hi/lo ============
// tile index = ctile*(KP/32) + t ; within-tile: lane*8 + j
// element = W[t*32 + (lane>>4)*8 + j][ctile*16 + (lane&15)], 0 if k >= K
__global__ __launch_bounds__(256) void pack_w_kernel(
    const float* __restrict__ W, int K, int KP,
    unsigned short* __restrict__ Ph, unsigned short* __restrict__ Pl)
{
    int idx = blockIdx.x * 256 + threadIdx.x;
    if (idx >= KP * 256) return;
    int tile = idx >> 9, w = idx & 511, lane = w >> 3, j = w & 7;
    int nk = KP >> 5;
    int ctile = tile / nk, t = tile % nk;
    int k = t * 32 + ((lane >> 4) << 3) + j;
    int n = (ctile << 4) + (lane & 15);
    float v = (k < K) ? W[(size_t)k * 256 + n] : 0.0f;
    unsigned short h, l;
    split_hilo(v, h, l);
    Ph[idx] = h;
    Pl[idx] = l;
}

// ===================== MFMA bf16x3 GEMM ====================================
// C[N x 256] = A[N x KP] @ W[KP x 256] (+bias). A as hi/lo bf16 row-major,
// W packed by pack_w_kernel. Block: 64 rows x 128 cols (grid.y=2), 4 waves,
// wave w = rows [w*16, w*16+16), 8 col-tiles of 16.
template <int KSTEPS, bool HILO>
__global__ __launch_bounds__(256) void mfma_gemm_kernel(
    const unsigned short* __restrict__ Ah, const unsigned short* __restrict__ Al,
    int lda,
    const unsigned short* __restrict__ Ph, const unsigned short* __restrict__ Pl,
    const float* __restrict__ bias,
    float* __restrict__ Cf,
    unsigned short* __restrict__ Ch, unsigned short* __restrict__ Cl,
    int ldc, int col_off, int Nrows)
{
    int tid = threadIdx.x;
    int wave = tid >> 6, lane = tid & 63;
    int quad = lane >> 4, m16 = lane & 15;
    int row = blockIdx.x * 64 + wave * 16 + m16;
    bool rowok = row < Nrows;
    int ctile0 = blockIdx.y * 8;

    f32x4 acc[8] = {};
    const unsigned short* arh = Ah + (size_t)row * lda;
    const unsigned short* arl = Al + (size_t)row * lda;

    for (int t = 0; t < KSTEPS; t++) {
        int k = t * 32 + quad * 8;
        bf16x8 a_h = {}, a_l = {};
        if (rowok) {
            a_h = *(const bf16x8*)(arh + k);
            a_l = *(const bf16x8*)(arl + k);
        }
        #pragma unroll
        for (int c = 0; c < 8; c++) {
            size_t wb = ((size_t)((ctile0 + c) * KSTEPS + t)) * 512 + lane * 8;
            bf16x8 b_h = *(const bf16x8*)(Ph + wb);
            bf16x8 b_l = *(const bf16x8*)(Pl + wb);
            acc[c] = __builtin_amdgcn_mfma_f32_16x16x32_bf16(a_h, b_h, acc[c], 0, 0, 0);
            acc[c] = __builtin_amdgcn_mfma_f32_16x16x32_bf16(a_l, b_h, acc[c], 0, 0, 0);
            acc[c] = __builtin_amdgcn_mfma_f32_16x16x32_bf16(a_h, b_l, acc[c], 0, 0, 0);
        }
    }

    // epilogue: D[row = quad*4 + r][col = lane&15] within each 16x16 tile
    #pragma unroll
    for (int c = 0; c < 8; c++) {
        int ocol = (ctile0 + c) * 16 + m16;
        float bv = bias ? bias[ocol] : 0.0f;
        #pragma unroll
        for (int r = 0; r < 4; r++) {
            int orow = blockIdx.x * 64 + wave * 16 + quad * 4 + r;
            if (orow >= Nrows) continue;
            float v = acc[c][r] + bv;
            size_t oidx = (size_t)orow * ldc + col_off + ocol;
            if (HILO) {
                unsigned short h, l;
                split_hilo(v, h, l);
                Ch[oidx] = h;
                Cl[oidx] = l;
            } else {
                Cf[oidx] = v;
            }
        }
    }
}

// ---------------- GAT per-node attention dots ------------------------------
__global__ __launch_bounds__(256) void gat_prep_kernel(
    const float* __restrict__ xh,
    const float* __restrict__ att_src, const float* __restrict__ att_dst,
    float* __restrict__ a_src, float* __restrict__ a_dst, int N)
{
    int n = blockIdx.x;
    int t = threadIdx.x;
    int h = t >> 6, c = t & 63;
    float v = xh[(size_t)n * 256 + t];
    float s = v * att_src[t];
    float d = v * att_dst[t];
    #pragma unroll
    for (int o = 32; o > 0; o >>= 1) {
        s += __shfl_down(s, o, 64);
        d += __shfl_down(d, o, 64);
    }
    if (c == 0) {
        a_src[n * 4 + h] = s;
        a_dst[n * 4 + h] = d;
    }
}

// ===== CSR aggregation: softmax + weighted sum + bias + ELU -> hi/lo =======
__global__ __launch_bounds__(256) void gat_agg_csr_kernel(
    const float* __restrict__ xh,
    const int* __restrict__ rowptr, const int* __restrict__ col,
    const float* __restrict__ a_src, const float* __restrict__ a_dst,
    const float* __restrict__ bias,
    unsigned short* __restrict__ outH, unsigned short* __restrict__ outL, int N)
{
    __shared__ float denom_sh[HEADS];
    int n = blockIdx.x;
    int t = threadIdx.x;
    int h = t >> 6, c = t & 63;
    int base = rowptr[n], end = rowptr[n + 1];
    float adst = a_dst[n * 4 + h];

    float part = 0.0f;
    for (int j = base + c; j < end; j += 64) {
        float l = a_src[col[j] * 4 + h] + adst;
        l = (l > 0.0f) ? l : 0.2f * l;
        part += __expf(l);
    }
    #pragma unroll
    for (int o = 32; o > 0; o >>= 1) part += __shfl_down(part, o, 64);
    if (c == 0) denom_sh[h] = part;
    __syncthreads();
    float inv = 1.0f / denom_sh[h];

    float acc = 0.0f;
    for (int j = base; j < end; j++) {
        int s = col[j];
        float l = a_src[s * 4 + h] + adst;
        l = (l > 0.0f) ? l : 0.2f * l;
        float w = __expf(l) * inv;
        acc += w * xh[(size_t)s * 256 + t];
    }
    float v = acc + bias[t];
    v = (v > 0.0f) ? v : (__expf(v) - 1.0f);
    unsigned short hh, ll;
    split_hilo(v, hh, ll);
    outH[(size_t)n * 256 + t] = hh;
    outL[(size_t)n * 256 + t] = ll;
}

// ===========================================================================

extern "C" void kernel_launch(void* const* d_in, const int* in_sizes, int n_in,
                              void* d_out, int out_size, void* d_ws, size_t ws_size,
                              hipStream_t stream)
{
    const float* node_feats = (const float*)d_in[0];
    const float* edge_attr  = (const float*)d_in[1];
    const float* Wnp = (const float*)d_in[2];
    const float* bnp = (const float*)d_in[3];
    const float* Wep = (const float*)d_in[4];
    const float* bep = (const float*)d_in[5];
    const float* Wg1 = (const float*)d_in[6];
    const float* as1 = (const float*)d_in[7];
    const float* ad1 = (const float*)d_in[8];
    const float* bg1 = (const float*)d_in[9];
    const float* Wg2 = (const float*)d_in[10];
    const float* as2 = (const float*)d_in[11];
    const float* ad2 = (const float*)d_in[12];
    const float* bg2 = (const float*)d_in[13];
    const float* Wo  = (const float*)d_in[14];
    const float* bo  = (const float*)d_in[15];
    const int*   ei  = (const int*)d_in[16];

    const int N = in_sizes[0] / 128;   // 50000
    const int E = in_sizes[16] / 2;    // 800000
    const int* src = ei;
    const int* dst = ei + E;
    const int nchunk = (N + 255) / 256;
    const int EN = E + N;

    typedef unsigned short u16;

    // ---- workspace layout (256B-aligned regions) ----
    char* base = (char*)d_ws;
    size_t off = 0;
    auto alloc = [&](size_t bytes) -> char* {
        char* p = base + off;
        off += (bytes + 255) & ~(size_t)255;
        return p;
    };
    float* xh = (float*)alloc((size_t)N * 256 * 4);        // f32 xh; hosts nf/nef aliases
    u16* x2H  = (u16*)alloc((size_t)N * 512 * 2);          // hosts x3H/x3L after GEMM3
    u16* x2L  = (u16*)alloc((size_t)N * 512 * 2);          // hosts x4H/x4L after GEMM3
    float* a_src = (float*)alloc((size_t)N * 4 * 4);
    float* a_dst = (float*)alloc((size_t)N * 4 * 4);
    u16* PnpH = (u16*)alloc(128 * 256 * 2);
    u16* PnpL = (u16*)alloc(128 * 256 * 2);
    u16* PepH = (u16*)alloc(32 * 256 * 2);
    u16* PepL = (u16*)alloc(32 * 256 * 2);
    u16* Pg1H = (u16*)alloc(512 * 256 * 2);
    u16* Pg1L = (u16*)alloc(512 * 256 * 2);
    u16* Pg2H = (u16*)alloc(256 * 256 * 2);
    u16* Pg2L = (u16*)alloc(256 * 256 * 2);
    u16* PoH  = (u16*)alloc(256 * 256 * 2);
    u16* PoL  = (u16*)alloc(256 * 256 * 2);
    int* cnt       = (int*)alloc((size_t)N * 4);
    int* rowptr    = (int*)alloc((size_t)(N + 1) * 4);
    int* fillptr   = (int*)alloc((size_t)N * 4);
    int* chunk_sum = (int*)alloc((size_t)nchunk * 4);
    int* chunk_off = (int*)alloc((size_t)nchunk * 4);
    int* colv      = (int*)alloc((size_t)EN * 4);
    int* eid       = (int*)alloc((size_t)EN * 4);

    // aliases inside xh region (dead before GEMM3 writes xh)
    u16* nfH  = (u16*)xh;
    u16* nfL  = nfH + (size_t)N * 128;
    u16* nefH = nfL + (size_t)N * 128;
    u16* nefL = nefH + (size_t)N * 32;
    // aliases inside x2 regions (x2 dead after GEMM3)
    u16* x3H = x2H;
    u16* x3L = x2H + (size_t)N * 256;
    u16* x4H = x2L;
    u16* x4L = x2L + (size_t)N * 256;

    float* out = (float*)d_out;
    dim3 ggrid((N + 63) / 64, 2);

    // ---- CSR build ----
    hipMemsetAsync(cnt, 0, (size_t)N * sizeof(int), stream);
    count_kernel<<<(E + 255) / 256, 256, 0, stream>>>(dst, cnt, E);
    scan1_kernel<<<nchunk, 256, 0, stream>>>(cnt, chunk_sum, N);
    scan2_kernel<<<1, 1, 0, stream>>>(chunk_sum, chunk_off, nchunk);
    scan3_kernel<<<nchunk, 256, 0, stream>>>(cnt, chunk_off, rowptr, fillptr, colv, eid, N);
    fill_kernel<<<(E + 255) / 256, 256, 0, stream>>>(src, dst, fillptr, colv, eid, E);

    // ---- input conversions + weight packing ----
    nef_csr_kernel<<<N, 64, 0, stream>>>(edge_attr, rowptr, eid, nefH, nefL, N);
    conv_hilo_kernel<<<((N * 128) / 2 + 255) / 256, 256, 0, stream>>>(
        node_feats, nfH, nfL, N * 128);
    pack_w_kernel<<<(128 * 256 + 255) / 256, 256, 0, stream>>>(Wnp, 128, 128, PnpH, PnpL);
    pack_w_kernel<<<(32 * 256 + 255) / 256, 256, 0, stream>>>(Wep, 16, 32, PepH, PepL);
    pack_w_kernel<<<(512 * 256 + 255) / 256, 256, 0, stream>>>(Wg1, 512, 512, Pg1H, Pg1L);
    pack_w_kernel<<<(256 * 256 + 255) / 256, 256, 0, stream>>>(Wg2, 256, 256, Pg2H, Pg2L);
    pack_w_kernel<<<(256 * 256 + 255) / 256, 256, 0, stream>>>(Wo, 256, 256, PoH, PoL);

    // ---- x2 = [ nf@Wnp + bnp | nef@Wep + bep ] -> x2H/x2L [N x 512] ----
    mfma_gemm_kernel<4, true><<<ggrid, 256, 0, stream>>>(
        nfH, nfL, 128, PnpH, PnpL, bnp, nullptr, x2H, x2L, 512, 0, N);
    mfma_gemm_kernel<1, true><<<ggrid, 256, 0, stream>>>(
        nefH, nefL, 32, PepH, PepL, bep, nullptr, x2H, x2L, 512, 256, N);

    // ---- GAT layer 1 ----
    mfma_gemm_kernel<16, false><<<ggrid, 256, 0, stream>>>(
        x2H, x2L, 512, Pg1H, Pg1L, nullptr, xh, nullptr, nullptr, 256, 0, N);
    gat_prep_kernel<<<N, 256, 0, stream>>>(xh, as1, ad1, a_src, a_dst, N);
    gat_agg_csr_kernel<<<N, 256, 0, stream>>>(
        xh, rowptr, colv, a_src, a_dst, bg1, x3H, x3L, N);

    // ---- GAT layer 2 ----
    mfma_gemm_kernel<8, false><<<ggrid, 256, 0, stream>>>(
        x3H, x3L, 256, Pg2H, Pg2L, nullptr, xh, nullptr, nullptr, 256, 0, N);
    gat_prep_kernel<<<N, 256, 0, stream>>>(xh, as2, ad2, a_src, a_dst, N);
    gat_agg_csr_kernel<<<N, 256, 0, stream>>>(
        xh, rowptr, colv, a_src, a_dst, bg2, x4H, x4L, N);

    // ---- out = x4 @ Wo + bo -> d_out (f32) ----
    mfma_gemm_kernel<8, false><<<ggrid, 256, 0, stream>>>(
        x4H, x4L, 256, PoH, PoL, bo, out, nullptr, nullptr, 256, 0, N);
}

// Round 5
// 887.899 us; speedup vs baseline: 2.5230x; 1.1660x over previous
//
#include <hip/hip_runtime.h>
#include <hip/hip_bf16.h>

// GNN: node_proj + edge scatter_mean/proj -> concat -> GAT(512->4x64) -> ELU
//      -> GAT(256->4x64) -> ELU -> out_proj. ALL tensors float32 (per ref).
// R4: (a) gat_agg restructured: 4 edges in flight per block, float4 row
//     gather, LDS cross-group combine (was: 1 dword/lane/edge serial).
//     (b) attention dots fused into MFMA GEMM epilogue (gat_prep deleted).

#define HEADS 4

typedef __attribute__((ext_vector_type(8))) short bf16x8;
typedef __attribute__((ext_vector_type(4))) float f32x4;

__device__ __forceinline__ unsigned short f2b(float v) {
    __hip_bfloat16 b = __float2bfloat16(v);
    return __builtin_bit_cast(unsigned short, b);
}
__device__ __forceinline__ float b2f(unsigned short u) {
    __hip_bfloat16 b = __builtin_bit_cast(__hip_bfloat16, u);
    return __bfloat162float(b);
}
__device__ __forceinline__ void split_hilo(float v, unsigned short& h, unsigned short& l) {
    h = f2b(v);
    l = f2b(v - b2f(h));
}

// ============================ CSR construction =============================

__global__ __launch_bounds__(256) void count_kernel(
    const int* __restrict__ dst, int* __restrict__ cnt, int E)
{
    int e = blockIdx.x * 256 + threadIdx.x;
    if (e < E) atomicAdd(&cnt[dst[e]], 1);
}

__global__ __launch_bounds__(256) void scan1_kernel(
    const int* __restrict__ cnt, int* __restrict__ chunk_sum, int N)
{
    __shared__ int sd[256];
    int t = threadIdx.x;
    int n = blockIdx.x * 256 + t;
    sd[t] = (n < N) ? (cnt[n] + 1) : 0;
    __syncthreads();
    for (int o = 128; o > 0; o >>= 1) {
        if (t < o) sd[t] += sd[t + o];
        __syncthreads();
    }
    if (t == 0) chunk_sum[blockIdx.x] = sd[0];
}

__global__ void scan2_kernel(const int* __restrict__ chunk_sum,
                             int* __restrict__ chunk_off, int nchunk)
{
    int acc = 0;
    for (int i = 0; i < nchunk; i++) {
        chunk_off[i] = acc;
        acc += chunk_sum[i];
    }
}

__global__ __launch_bounds__(256) void scan3_kernel(
    const int* __restrict__ cnt, const int* __restrict__ chunk_off,
    int* __restrict__ rowptr, int* __restrict__ fillptr,
    int* __restrict__ col, int* __restrict__ eid, int N)
{
    __shared__ int sd[256];
    int t = threadIdx.x;
    int n = blockIdx.x * 256 + t;
    int v = (n < N) ? (cnt[n] + 1) : 0;
    sd[t] = v;
    __syncthreads();
    for (int o = 1; o < 256; o <<= 1) {
        int x = (t >= o) ? sd[t - o] : 0;
        __syncthreads();
        sd[t] += x;
        __syncthreads();
    }
    if (n < N) {
        int incl = sd[t];
        int r = chunk_off[blockIdx.x] + incl - v;
        rowptr[n] = r;
        col[r] = n;        // self loop, first entry
        eid[r] = -1;
        fillptr[n] = r + 1;
        if (n == N - 1) rowptr[N] = chunk_off[blockIdx.x] + incl;
    }
}

__global__ __launch_bounds__(256) void fill_kernel(
    const int* __restrict__ src, const int* __restrict__ dst,
    int* __restrict__ fillptr, int* __restrict__ col, int* __restrict__ eid, int E)
{
    int e = blockIdx.x * 256 + threadIdx.x;
    if (e >= E) return;
    int d = dst[e];
    int p = atomicAdd(&fillptr[d], 1);
    col[p] = src[e];
    eid[p] = e;
}

// ====== edge_attr scatter-mean via CSR -> hi/lo bf16 [N x 32] (K-padded) ===
__global__ __launch_bounds__(64) void nef_csr_kernel(
    const float* __restrict__ ea, const int* __restrict__ rowptr,
    const int* __restrict__ eid,
    unsigned short* __restrict__ nefH, unsigned short* __restrict__ nefL, int N)
{
    int n = blockIdx.x;
    int t = threadIdx.x;
    int f = t & 15, g = t >> 4;
    int base = rowptr[n], end = rowptr[n + 1];
    int deg = end - base - 1;
    float acc = 0.0f;
    for (int j = base + 1 + g; j < end; j += 4) {
        int e = eid[j];
        acc += ea[(size_t)e * 16 + f];
    }
    acc += __shfl_down(acc, 32, 64);
    acc += __shfl_down(acc, 16, 64);
    if (t < 16) {
        float v = acc / fmaxf((float)deg, 1.0f);
        unsigned short h, l;
        split_hilo(v, h, l);
        nefH[(size_t)n * 32 + t] = h;
        nefL[(size_t)n * 32 + t] = l;
    } else if (t < 32) {
        nefH[(size_t)n * 32 + t] = 0;
        nefL[(size_t)n * 32 + t] = 0;
    }
}

// ============ convert f32 -> hi/lo bf16 (2 elems per thread) ===============
__global__ __launch_bounds__(256) void conv_hilo_kernel(
    const float* __restrict__ X,
    unsigned short* __restrict__ H, unsigned short* __restrict__ L, int total)
{
    int base = (blockIdx.x * 256 + threadIdx.x) * 2;
    if (base >= total) return;
    #pragma unroll
    for (int i = 0; i < 2; i++) {
        unsigned short h, l;
        split_hilo(X[base + i], h, l);
        H[base + i] = h;
        L[base + i] = l;
    }
}

// ============ pack weights [K x 256] -> B-fragment order, hi/lo ============
__global__ __launch_bounds__(256) void pack_w_kernel(
    const float* __restrict__ W, int K, int KP,
    unsigned short* __restrict__ Ph, unsigned short* __restrict__ Pl)
{
    int idx = blockIdx.x * 256 + threadIdx.x;
    if (idx >= KP * 256) return;
    int tile = idx >> 9, w = idx & 511, lane = w >> 3, j = w & 7;
    int nk = KP >> 5;
    int ctile = tile / nk, t = tile % nk;
    int k = t * 32 + ((lane >> 4) << 3) + j;
    int n = (ctile << 4) + (lane & 15);
    float v = (k < K) ? W[(size_t)k * 256 + n] : 0.0f;
    unsigned short h, l;
    split_hilo(v, h, l);
    Ph[idx] = h;
    Pl[idx] = l;
}

// ===================== MFMA bf16x3 GEMM ====================================
// C[N x 256] = A[N x KP] @ W[KP x 256] (+bias). Block: 64 rows x 128 cols
// (grid.y=2), 4 waves. FUSE_ATT: also compute per-row per-head attention
// dots from accumulators and atomically add into a_srcO/a_dstO (pre-zeroed;
// exactly 2 contributions per address -> deterministic).
template <int KSTEPS, bool HILO, bool FUSE_ATT>
__global__ __launch_bounds__(256) void mfma_gemm_kernel(
    const unsigned short* __restrict__ Ah, const unsigned short* __restrict__ Al,
    int lda,
    const unsigned short* __restrict__ Ph, const unsigned short* __restrict__ Pl,
    const float* __restrict__ bias,
    float* __restrict__ Cf,
    unsigned short* __restrict__ Ch, unsigned short* __restrict__ Cl,
    int ldc, int col_off, int Nrows,
    const float* __restrict__ att_src, const float* __restrict__ att_dst,
    float* __restrict__ a_srcO, float* __restrict__ a_dstO)
{
    int tid = threadIdx.x;
    int wave = tid >> 6, lane = tid & 63;
    int quad = lane >> 4, m16 = lane & 15;
    int row = blockIdx.x * 64 + wave * 16 + m16;
    bool rowok = row < Nrows;
    int ctile0 = blockIdx.y * 8;

    f32x4 acc[8] = {};
    const unsigned short* arh = Ah + (size_t)row * lda;
    const unsigned short* arl = Al + (size_t)row * lda;

    for (int t = 0; t < KSTEPS; t++) {
        int k = t * 32 + quad * 8;
        bf16x8 a_h = {}, a_l = {};
        if (rowok) {
            a_h = *(const bf16x8*)(arh + k);
            a_l = *(const bf16x8*)(arl + k);
        }
        #pragma unroll
        for (int c = 0; c < 8; c++) {
            size_t wb = ((size_t)((ctile0 + c) * KSTEPS + t)) * 512 + lane * 8;
            bf16x8 b_h = *(const bf16x8*)(Ph + wb);
            bf16x8 b_l = *(const bf16x8*)(Pl + wb);
            acc[c] = __builtin_amdgcn_mfma_f32_16x16x32_bf16(a_h, b_h, acc[c], 0, 0, 0);
            acc[c] = __builtin_amdgcn_mfma_f32_16x16x32_bf16(a_l, b_h, acc[c], 0, 0, 0);
            acc[c] = __builtin_amdgcn_mfma_f32_16x16x32_bf16(a_h, b_l, acc[c], 0, 0, 0);
        }
    }

    // main epilogue: D[row = quad*4 + r][col = lane&15] within each tile
    #pragma unroll
    for (int c = 0; c < 8; c++) {
        int ocol = (ctile0 + c) * 16 + m16;
        float bv = bias ? bias[ocol] : 0.0f;
        #pragma unroll
        for (int r = 0; r < 4; r++) {
            int orow = blockIdx.x * 64 + wave * 16 + quad * 4 + r;
            if (orow >= Nrows) continue;
            float v = acc[c][r] + bv;
            size_t oidx = (size_t)orow * ldc + col_off + ocol;
            if (HILO) {
                unsigned short h, l;
                split_hilo(v, h, l);
                Ch[oidx] = h;
                Cl[oidx] = l;
            } else {
                Cf[oidx] = v;
            }
        }
    }

    if (FUSE_ATT) {
        // per-row (r), per-local-head (hl=c>>2) attention dot partials
        float ps[4][2] = {}, pd[4][2] = {};
        #pragma unroll
        for (int c = 0; c < 8; c++) {
            int ocol = (ctile0 + c) * 16 + m16;
            float asv = att_src[ocol];
            float adv = att_dst[ocol];
            int hl = c >> 2;
            #pragma unroll
            for (int r = 0; r < 4; r++) {
                ps[r][hl] += acc[c][r] * asv;
                pd[r][hl] += acc[c][r] * adv;
            }
        }
        #pragma unroll
        for (int r = 0; r < 4; r++) {
            #pragma unroll
            for (int hl = 0; hl < 2; hl++) {
                float s = ps[r][hl], d = pd[r][hl];
                #pragma unroll
                for (int o = 8; o > 0; o >>= 1) {
                    s += __shfl_down(s, o, 64);
                    d += __shfl_down(d, o, 64);
                }
                if (m16 == 0) {
                    int orow = blockIdx.x * 64 + wave * 16 + quad * 4 + r;
                    if (orow < Nrows) {
                        int gh = blockIdx.y * 2 + hl;
                        atomicAdd(&a_srcO[orow * 4 + gh], s);
                        atomicAdd(&a_dstO[orow * 4 + gh], d);
                    }
                }
            }
        }
    }
}

// ===== CSR aggregation: softmax + weighted sum + bias + ELU -> hi/lo =======
// one block per dst node; 4 waves process 4 edges concurrently; lane covers
// 4 consecutive columns via float4 gather; LDS combine across waves.
__global__ __launch_bounds__(256) void gat_agg_csr_kernel(
    const float* __restrict__ xh,
    const int* __restrict__ rowptr, const int* __restrict__ col,
    const float* __restrict__ a_src, const float* __restrict__ a_dst,
    const float* __restrict__ bias,
    unsigned short* __restrict__ outH, unsigned short* __restrict__ outL, int N)
{
    __shared__ float denom_sh[HEADS];
    __shared__ float red[1024];
    int n = blockIdx.x;
    int t = threadIdx.x;
    int base = rowptr[n], end = rowptr[n + 1];

    // pass 1: denominator per head (wave h1 = head h1, lanes stride edges)
    int h1 = t >> 6, c1 = t & 63;
    float adst1 = a_dst[n * 4 + h1];
    float part = 0.0f;
    for (int j = base + c1; j < end; j += 64) {
        float l = a_src[col[j] * 4 + h1] + adst1;
        l = (l > 0.0f) ? l : 0.2f * l;
        part += __expf(l);
    }
    #pragma unroll
    for (int o = 32; o > 0; o >>= 1) part += __shfl_down(part, o, 64);
    if (c1 == 0) denom_sh[h1] = part;
    __syncthreads();

    // pass 2: group g handles edges base+g, base+g+4, ...; lane covers
    // columns 4c..4c+3 (head h = c>>4)
    int g = t >> 6, c = t & 63;
    int h = c >> 4;
    float inv = 1.0f / denom_sh[h];
    float adst2 = a_dst[n * 4 + h];
    float4 acc = {0.0f, 0.0f, 0.0f, 0.0f};
    for (int j = base + g; j < end; j += 4) {
        int s = col[j];
        float l = a_src[s * 4 + h] + adst2;
        l = (l > 0.0f) ? l : 0.2f * l;
        float w = __expf(l) * inv;
        float4 x = *(const float4*)(xh + (size_t)s * 256 + (c << 2));
        acc.x += w * x.x;
        acc.y += w * x.y;
        acc.z += w * x.z;
        acc.w += w * x.w;
    }
    *(float4*)(&red[g * 256 + (c << 2)]) = acc;
    __syncthreads();

    // combine groups + bias + ELU + hi/lo split; thread t owns column t
    float v = red[t] + red[256 + t] + red[512 + t] + red[768 + t] + bias[t];
    v = (v > 0.0f) ? v : (__expf(v) - 1.0f);
    unsigned short hh, ll;
    split_hilo(v, hh, ll);
    outH[(size_t)n * 256 + t] = hh;
    outL[(size_t)n * 256 + t] = ll;
}

// ===========================================================================

extern "C" void kernel_launch(void* const* d_in, const int* in_sizes, int n_in,
                              void* d_out, int out_size, void* d_ws, size_t ws_size,
                              hipStream_t stream)
{
    const float* node_feats = (const float*)d_in[0];
    const float* edge_attr  = (const float*)d_in[1];
    const float* Wnp = (const float*)d_in[2];
    const float* bnp = (const float*)d_in[3];
    const float* Wep = (const float*)d_in[4];
    const float* bep = (const float*)d_in[5];
    const float* Wg1 = (const float*)d_in[6];
    const float* as1 = (const float*)d_in[7];
    const float* ad1 = (const float*)d_in[8];
    const float* bg1 = (const float*)d_in[9];
    const float* Wg2 = (const float*)d_in[10];
    const float* as2 = (const float*)d_in[11];
    const float* ad2 = (const float*)d_in[12];
    const float* bg2 = (const float*)d_in[13];
    const float* Wo  = (const float*)d_in[14];
    const float* bo  = (const float*)d_in[15];
    const int*   ei  = (const int*)d_in[16];

    const int N = in_sizes[0] / 128;   // 50000
    const int E = in_sizes[16] / 2;    // 800000
    const int* src = ei;
    const int* dst = ei + E;
    const int nchunk = (N + 255) / 256;
    const int EN = E + N;

    typedef unsigned short u16;

    // ---- workspace layout (256B-aligned regions) ----
    char* base = (char*)d_ws;
    size_t off = 0;
    auto alloc = [&](size_t bytes) -> char* {
        char* p = base + off;
        off += (bytes + 255) & ~(size_t)255;
        return p;
    };
    float* xh = (float*)alloc((size_t)N * 256 * 4);        // f32 xh; hosts nf/nef aliases
    u16* x2H  = (u16*)alloc((size_t)N * 512 * 2);          // hosts x3H/x3L after GEMM3
    u16* x2L  = (u16*)alloc((size_t)N * 512 * 2);          // hosts x4H/x4L after GEMM3
    float* a_src = (float*)alloc((size_t)N * 4 * 4);
    float* a_dst = (float*)alloc((size_t)N * 4 * 4);
    u16* PnpH = (u16*)alloc(128 * 256 * 2);
    u16* PnpL = (u16*)alloc(128 * 256 * 2);
    u16* PepH = (u16*)alloc(32 * 256 * 2);
    u16* PepL = (u16*)alloc(32 * 256 * 2);
    u16* Pg1H = (u16*)alloc(512 * 256 * 2);
    u16* Pg1L = (u16*)alloc(512 * 256 * 2);
    u16* Pg2H = (u16*)alloc(256 * 256 * 2);
    u16* Pg2L = (u16*)alloc(256 * 256 * 2);
    u16* PoH  = (u16*)alloc(256 * 256 * 2);
    u16* PoL  = (u16*)alloc(256 * 256 * 2);
    int* cnt       = (int*)alloc((size_t)N * 4);
    int* rowptr    = (int*)alloc((size_t)(N + 1) * 4);
    int* fillptr   = (int*)alloc((size_t)N * 4);
    int* chunk_sum = (int*)alloc((size_t)nchunk * 4);
    int* chunk_off = (int*)alloc((size_t)nchunk * 4);
    int* colv      = (int*)alloc((size_t)EN * 4);
    int* eid       = (int*)alloc((size_t)EN * 4);

    // aliases inside xh region (dead before GEMM3 writes xh)
    u16* nfH  = (u16*)xh;
    u16* nfL  = nfH + (size_t)N * 128;
    u16* nefH = nfL + (size_t)N * 128;
    u16* nefL = nefH + (size_t)N * 32;
    // aliases inside x2 regions (x2 dead after GEMM3)
    u16* x3H = x2H;
    u16* x3L = x2H + (size_t)N * 256;
    u16* x4H = x2L;
    u16* x4L = x2L + (size_t)N * 256;

    float* out = (float*)d_out;
    dim3 ggrid((N + 63) / 64, 2);

    // ---- CSR build ----
    hipMemsetAsync(cnt, 0, (size_t)N * sizeof(int), stream);
    count_kernel<<<(E + 255) / 256, 256, 0, stream>>>(dst, cnt, E);
    scan1_kernel<<<nchunk, 256, 0, stream>>>(cnt, chunk_sum, N);
    scan2_kernel<<<1, 1, 0, stream>>>(chunk_sum, chunk_off, nchunk);
    scan3_kernel<<<nchunk, 256, 0, stream>>>(cnt, chunk_off, rowptr, fillptr, colv, eid, N);
    fill_kernel<<<(E + 255) / 256, 256, 0, stream>>>(src, dst, fillptr, colv, eid, E);

    // ---- input conversions + weight packing ----
    nef_csr_kernel<<<N, 64, 0, stream>>>(edge_attr, rowptr, eid, nefH, nefL, N);
    conv_hilo_kernel<<<((N * 128) / 2 + 255) / 256, 256, 0, stream>>>(
        node_feats, nfH, nfL, N * 128);
    pack_w_kernel<<<(128 * 256 + 255) / 256, 256, 0, stream>>>(Wnp, 128, 128, PnpH, PnpL);
    pack_w_kernel<<<(32 * 256 + 255) / 256, 256, 0, stream>>>(Wep, 16, 32, PepH, PepL);
    pack_w_kernel<<<(512 * 256 + 255) / 256, 256, 0, stream>>>(Wg1, 512, 512, Pg1H, Pg1L);
    pack_w_kernel<<<(256 * 256 + 255) / 256, 256, 0, stream>>>(Wg2, 256, 256, Pg2H, Pg2L);
    pack_w_kernel<<<(256 * 256 + 255) / 256, 256, 0, stream>>>(Wo, 256, 256, PoH, PoL);

    // ---- x2 = [ nf@Wnp + bnp | nef@Wep + bep ] -> x2H/x2L [N x 512] ----
    mfma_gemm_kernel<4, true, false><<<ggrid, 256, 0, stream>>>(
        nfH, nfL, 128, PnpH, PnpL, bnp, nullptr, x2H, x2L, 512, 0, N,
        nullptr, nullptr, nullptr, nullptr);
    mfma_gemm_kernel<1, true, false><<<ggrid, 256, 0, stream>>>(
        nefH, nefL, 32, PepH, PepL, bep, nullptr, x2H, x2L, 512, 256, N,
        nullptr, nullptr, nullptr, nullptr);

    // ---- GAT layer 1: GEMM (+fused att dots) -> agg ----
    hipMemsetAsync(a_src, 0, (size_t)N * 4 * sizeof(float), stream);
    hipMemsetAsync(a_dst, 0, (size_t)N * 4 * sizeof(float), stream);
    mfma_gemm_kernel<16, false, true><<<ggrid, 256, 0, stream>>>(
        x2H, x2L, 512, Pg1H, Pg1L, nullptr, xh, nullptr, nullptr, 256, 0, N,
        as1, ad1, a_src, a_dst);
    gat_agg_csr_kernel<<<N, 256, 0, stream>>>(
        xh, rowptr, colv, a_src, a_dst, bg1, x3H, x3L, N);

    // ---- GAT layer 2 ----
    hipMemsetAsync(a_src, 0, (size_t)N * 4 * sizeof(float), stream);
    hipMemsetAsync(a_dst, 0, (size_t)N * 4 * sizeof(float), stream);
    mfma_gemm_kernel<8, false, true><<<ggrid, 256, 0, stream>>>(
        x3H, x3L, 256, Pg2H, Pg2L, nullptr, xh, nullptr, nullptr, 256, 0, N,
        as2, ad2, a_src, a_dst);
    gat_agg_csr_kernel<<<N, 256, 0, stream>>>(
        xh, rowptr, colv, a_src, a_dst, bg2, x4H, x4L, N);

    // ---- out = x4 @ Wo + bo -> d_out (f32) ----
    mfma_gemm_kernel<8, false, false><<<ggrid, 256, 0, stream>>>(
        x4H, x4L, 256, PoH, PoL, bo, out, nullptr, nullptr, 256, 0, N,
        nullptr, nullptr, nullptr, nullptr);
}